// Round 11
// baseline (90.942 us; speedup 1.0000x reference)
//
#include <hip/hip_runtime.h>

#define BC 88                        // B*C channels
#define NVOX 262144                  // 64^3
#define KBINS 20
#define NEDGE 21                     // contiguous bin edges e[0..20]
#define THREADS 256
#define NBLOCKS 2048                 // 8 blocks/CU -> 32 waves/CU (R7-best TLP)
#define CPB 11                       // chunks (1024 elems) per block; zero tail
#define CPC 256                      // chunks per channel
#define HSTRIDE 23                   // 22 slots + pad; gcd(23,32)=1
#define ROWSET (64 * HSTRIDE)

// Three-pipe split: a-hist via 1 ds_atomic/pair (DS), b-hist via ballot-
// popcount CDF in wave-uniform SGPR counters (VALU cmp + SALU bcnt/add).
// hist[k] = count_a[k] - (cdf_b[k+1] - cdf_b[k]). No memset, no global atomics.
__global__ void __launch_bounds__(THREADS)
binloss_main(const float* __restrict__ inp, const float* __restrict__ tar,
             const float* __restrict__ br, int* __restrict__ slot,
             int* __restrict__ bslot, float* __restrict__ partials)
{
    __shared__ int   rows[2 * ROWSET];      // a-counts: seg0/seg1 per-lane rows
    __shared__ int   bcnt[2][4][NEDGE];     // b-CDF: per segment x wave
    __shared__ int   qsum[2][4][KBINS];
    __shared__ float wsum[4];

    const int tid = threadIdx.x, lane = tid & 63, wv = tid >> 6;
    for (int i = tid; i < 2 * ROWSET; i += THREADS) rows[i] = 0;
    if (tid < 2 * 4 * NEDGE) ((int*)bcnt)[tid] = 0;

    // edges -> uniform scalar regs (exact reference compare semantics for b)
    float e[NEDGE];
#pragma unroll
    for (int j = 0; j < KBINS; ++j) e[j] = br[2 * j];
    e[KBINS] = br[2 * KBINS - 1];
    const float inv_w  = (float)KBINS / (e[KBINS] - e[0]);
    const float shift1 = 1.0f - e[0] * inv_w;
    const float tmax   = 21.5f;
    __syncthreads();

    const int fc  = blockIdx.x * CPB;
    const int ch0 = fc >> 8;                // / CPC
    const int rem = fc & (CPC - 1);
    const int n1  = (rem + CPB > CPC) ? (CPC - rem) : CPB;  // chunks in ch0

    const float4* pa = (const float4*)inp + (size_t)fc * 256 + tid;
    const float4* pb = (const float4*)tar + (size_t)fc * 256 + tid;

    int* r0 = &rows[lane * HSTRIDE];
    int* r1 = r0 + ROWSET;

    int c[NEDGE];                           // wave-uniform -> SGPRs
#pragma unroll
    for (int j = 0; j < NEDGE; ++j) c[j] = 0;

    float s_lin = 0.f, s_quad = 0.f;

#pragma unroll
    for (int k = 0; k < CPB; ++k) {
        float4 a = pa[k * 256];
        float4 b = pb[k * 256];
        if (k == n1) {                      // uniform: channel boundary flush
            if (lane == 0)
#pragma unroll
                for (int j = 0; j < NEDGE; ++j) bcnt[0][wv][j] = c[j];
#pragma unroll
            for (int j = 0; j < NEDGE; ++j) c[j] = 0;
        }
        int* rw = (k < n1) ? r0 : r1;       // uniform select
#pragma unroll
        for (int q = 0; q < 4; ++q) {
            float av = (&a.x)[q], bv = (&b.x)[q];
            float d = fabsf(av - bv);
            s_lin += fmaxf(d, 1.0f);        // -1 hoisted out
            float m = fminf(d, 1.0f);
            s_quad  = __builtin_fmaf(m, m, s_quad);
            // a: med3 arithmetic bin -> DS pipe (slots 0,21 trash)
            int sa = (int)__builtin_amdgcn_fmed3f(__builtin_fmaf(av, inv_w, shift1), 0.0f, tmax);
            atomicAdd(&rw[sa], 1);
            // b: ballot CDF -> VALU cmp + SALU bcnt/add
#pragma unroll
            for (int j = 0; j < NEDGE; ++j)
                c[j] += (int)__popcll(__ballot(bv < e[j]));
        }
    }
    {
        const int seg = (n1 < CPB) ? 1 : 0; // tail segment flush
        if (lane == 0)
#pragma unroll
            for (int j = 0; j < NEDGE; ++j) bcnt[seg][wv][j] = c[j];
    }

    // SmoothL1 wave(64) + cross-wave reduce
    float sl1 = (s_lin - (float)(CPB * 4)) + 0.5f * s_quad;
#pragma unroll
    for (int off = 32; off > 0; off >>= 1) sl1 += __shfl_down(sl1, off, 64);
    if (lane == 0) wsum[wv] = sl1;
    __syncthreads();

    // stage 1: a-rows quarter sums
    if (tid < 160) {
        const int set = tid / 80, r = tid % 80;
        const int qr = r / KBINS, j = r % KBINS;
        int s = 0;
#pragma unroll
        for (int rr = qr * 16; rr < qr * 16 + 16; ++rr)
            s += rows[set * ROWSET + rr * HSTRIDE + 1 + j];
        qsum[set][qr][j] = s;
    }
    if (tid == 0)
        partials[blockIdx.x] = wsum[0] + wsum[1] + wsum[2] + wsum[3];
    __syncthreads();

    // stage 2: hist = a_count - b_cdf_diff; plain slot writes
    if (tid < 2 * KBINS) {
        const int set = tid / KBINS, j = tid % KBINS;
        int ac  = qsum[set][0][j] + qsum[set][1][j] + qsum[set][2][j] + qsum[set][3][j];
        int lo  = bcnt[set][0][j]     + bcnt[set][1][j]     + bcnt[set][2][j]     + bcnt[set][3][j];
        int hi  = bcnt[set][0][j + 1] + bcnt[set][1][j + 1] + bcnt[set][2][j + 1] + bcnt[set][3][j + 1];
        int v = ac - (hi - lo);
        if (set == 0)          slot[blockIdx.x * KBINS + j] = v;   // seg0 -> ch0
        else if (n1 < CPB)     bslot[(ch0 + 1) * KBINS + j] = v;   // seg1 -> ch0+1
    }
    if (rem == 0 && tid < KBINS) bslot[ch0 * KBINS + tid] = 0;     // aligned start
}

__global__ void __launch_bounds__(256)
binloss_final(const int* __restrict__ slot, const int* __restrict__ bslot,
              const float* __restrict__ partials, float* __restrict__ out)
{
    __shared__ double r1[256];
    __shared__ double r2[256];
    const int tid = threadIdx.x;
    double s1 = 0.0, s2 = 0.0;
    for (int i = tid; i < NBLOCKS; i += 256) s1 += (double)partials[i];
    for (int i = tid; i < BC * KBINS; i += 256) {
        const int c = i / KBINS, j = i - c * KBINS;
        const int b0 = (256 * c + 10) / 11;             // ceil(256c/11)
        const int b1 = (256 * (c + 1) + 10) / 11;
        int s = bslot[c * KBINS + j];
        for (int b = b0; b < b1; ++b) s += slot[b * KBINS + j];
        s2 += fabs((double)s);
    }
    r1[tid] = s1; r2[tid] = s2;
    __syncthreads();
    for (int off = 128; off > 0; off >>= 1) {
        if (tid < off) { r1[tid] += r1[tid + off]; r2[tid] += r2[tid + off]; }
        __syncthreads();
    }
    if (tid == 0) {
        const double ntot  = (double)BC * (double)NVOX;
        double loss1 = r1[0] / ntot;
        double loss2 = r2[0] / ((double)NVOX * (double)(BC * KBINS));
        out[0] = (float)(0.5 * loss1 + 0.5 * loss2);
    }
}

extern "C" void kernel_launch(void* const* d_in, const int* in_sizes, int n_in,
                              void* d_out, int out_size, void* d_ws, size_t ws_size,
                              hipStream_t stream) {
    const float* inp = (const float*)d_in[0];
    const float* tar = (const float*)d_in[1];
    const float* br  = (const float*)d_in[2];

    int*   slot     = (int*)d_ws;                       // 2048*20 ints (160 KB)
    int*   bslot    = slot + NBLOCKS * KBINS;           // 88*20 ints
    float* partials = (float*)(bslot + BC * KBINS);     // 2048 floats
    // every ws byte above is written unconditionally each call -> no memset

    binloss_main<<<NBLOCKS, THREADS, 0, stream>>>(inp, tar, br, slot, bslot, partials);
    binloss_final<<<1, 256, 0, stream>>>(slot, bslot, partials, (float*)d_out);
}

// Round 12
// 65.790 us; speedup vs baseline: 1.3823x; 1.3823x over previous
//
#include <hip/hip_runtime.h>

#define BC 88                        // B*C channels
#define NVOX 262144                  // 64^3
#define KBINS 20
#define THREADS 256
#define NBLOCKS 2048                 // 8 blocks/CU -> 32 waves/CU (R7-best TLP)
#define CPB 11                       // chunks (1024 elems) per block; zero tail
#define CPC 256                      // chunks per channel
#define HSTRIDE 23                   // 22 slots + pad; gcd(23,32)=1
#define ROWSET (64 * HSTRIDE)

// R7's proven inner loop (2 ds_atomic/pair, med3 binning, absmax 0.0 x5) +
// slot-write epilogue: no global atomics, no memset dispatch (every ws byte
// is unconditionally written each call -> poison-safe).
__global__ void __launch_bounds__(THREADS)
binloss_main(const float* __restrict__ inp, const float* __restrict__ tar,
             const float* __restrict__ br, int* __restrict__ slot,
             int* __restrict__ bslot, float* __restrict__ partials)
{
    __shared__ int   rows[2 * ROWSET];        // 11776 B: seg0 / seg1 rowsets
    __shared__ int   qsum[2][4][KBINS];
    __shared__ float wsum[THREADS / 64];

    const int tid  = threadIdx.x;
    const int lane = tid & 63;
    for (int i = tid; i < 2 * ROWSET; i += THREADS) rows[i] = 0;

    // uniform scalar loads; +1 folded so (int) truncation == floor
    const float e0     = br[0];
    const float eK     = br[2 * KBINS - 1];
    const float inv_w  = (float)KBINS / (eK - e0);
    const float shift1 = 1.0f - e0 * inv_w;
    const float tmax   = 21.5f;
    __syncthreads();

    const int fc  = blockIdx.x * CPB;
    const int ch0 = fc >> 8;                  // / CPC
    const int rem = fc & (CPC - 1);
    const int n1  = (rem + CPB > CPC) ? (CPC - rem) : CPB;   // chunks in ch0

    const float4* pa = (const float4*)inp + (size_t)fc * 256 + tid;
    const float4* pb = (const float4*)tar + (size_t)fc * 256 + tid;

    int* r0 = &rows[lane * HSTRIDE];
    int* r1 = r0 + ROWSET;

    float s_lin = 0.f, s_quad = 0.f;

#pragma unroll 2
    for (int k = 0; k < CPB; ++k) {
        float4 a = pa[k * 256];
        float4 b = pb[k * 256];
        int* rw = (k < n1) ? r0 : r1;                        // uniform select
#pragma unroll
        for (int q = 0; q < 4; ++q) {
            float av = (&a.x)[q], bv = (&b.x)[q];
            float d = fabsf(av - bv);
            s_lin += fmaxf(d, 1.0f);                         // -1 hoisted out
            float m = fminf(d, 1.0f);
            s_quad  = __builtin_fmaf(m, m, s_quad);
            int sa = (int)__builtin_amdgcn_fmed3f(__builtin_fmaf(av, inv_w, shift1), 0.0f, tmax);
            int sb = (int)__builtin_amdgcn_fmed3f(__builtin_fmaf(bv, inv_w, shift1), 0.0f, tmax);
            atomicAdd(&rw[sa], 1);                           // slots 0,21 = trash
            atomicAdd(&rw[sb], -1);
        }
    }

    // SmoothL1 wave(64) + cross-wave reduce
    float sl1 = (s_lin - (float)(CPB * 4)) + 0.5f * s_quad;
#pragma unroll
    for (int off = 32; off > 0; off >>= 1) sl1 += __shfl_down(sl1, off, 64);
    if (lane == 0) wsum[tid >> 6] = sl1;
    __syncthreads();

    // stage 1: 160 threads sum 16 rows each (set x quarter x bin)
    if (tid < 160) {
        const int set = tid / 80, r = tid % 80;
        const int qr = r / KBINS, j = r % KBINS;
        int s = 0;
#pragma unroll
        for (int rr = qr * 16; rr < qr * 16 + 16; ++rr)
            s += rows[set * ROWSET + rr * HSTRIDE + 1 + j];
        qsum[set][qr][j] = s;
    }
    if (tid == 0)
        partials[blockIdx.x] = wsum[0] + wsum[1] + wsum[2] + wsum[3];
    __syncthreads();

    // stage 2: combine quarters; plain slot writes (no atomics, no memset)
    if (tid < 2 * KBINS) {
        const int set = tid / KBINS, j = tid % KBINS;
        int v = qsum[set][0][j] + qsum[set][1][j] + qsum[set][2][j] + qsum[set][3][j];
        if (set == 0)          slot[blockIdx.x * KBINS + j] = v;     // seg0 -> ch0
        else if (n1 < CPB)     bslot[(ch0 + 1) * KBINS + j] = v;     // seg1 -> ch0+1
    }
    if (rem == 0 && tid < KBINS) bslot[ch0 * KBINS + tid] = 0;       // aligned start
}

__global__ void __launch_bounds__(256)
binloss_final(const int* __restrict__ slot, const int* __restrict__ bslot,
              const float* __restrict__ partials, float* __restrict__ out)
{
    __shared__ double r1[256];
    __shared__ double r2[256];
    const int tid = threadIdx.x;
    double s1 = 0.0, s2 = 0.0;
    for (int i = tid; i < NBLOCKS; i += 256) s1 += (double)partials[i];
    for (int i = tid; i < BC * KBINS; i += 256) {
        const int c = i / KBINS, j = i - c * KBINS;
        const int b0 = (256 * c + 10) / 11;                 // ceil(256c/11)
        const int b1 = (256 * (c + 1) + 10) / 11;
        int s = bslot[c * KBINS + j];
        for (int b = b0; b < b1; ++b) s += slot[b * KBINS + j];
        s2 += fabs((double)s);
    }
    r1[tid] = s1; r2[tid] = s2;
    __syncthreads();
    for (int off = 128; off > 0; off >>= 1) {
        if (tid < off) { r1[tid] += r1[tid + off]; r2[tid] += r2[tid + off]; }
        __syncthreads();
    }
    if (tid == 0) {
        const double ntot  = (double)BC * (double)NVOX;
        double loss1 = r1[0] / ntot;
        double loss2 = r2[0] / ((double)NVOX * (double)(BC * KBINS));
        out[0] = (float)(0.5 * loss1 + 0.5 * loss2);
    }
}

extern "C" void kernel_launch(void* const* d_in, const int* in_sizes, int n_in,
                              void* d_out, int out_size, void* d_ws, size_t ws_size,
                              hipStream_t stream) {
    const float* inp = (const float*)d_in[0];
    const float* tar = (const float*)d_in[1];
    const float* br  = (const float*)d_in[2];

    int*   slot     = (int*)d_ws;                       // 2048*20 ints (160 KB)
    int*   bslot    = slot + NBLOCKS * KBINS;           // 88*20 ints
    float* partials = (float*)(bslot + BC * KBINS);     // 2048 floats
    // every ws byte above is written unconditionally each call -> no memset

    binloss_main<<<NBLOCKS, THREADS, 0, stream>>>(inp, tar, br, slot, bslot, partials);
    binloss_final<<<1, 256, 0, stream>>>(slot, bslot, partials, (float*)d_out);
}

// Round 13
// 46.149 us; speedup vs baseline: 1.9706x; 1.4256x over previous
//
#include <hip/hip_runtime.h>

#define BC 88                        // B*C channels
#define NVOX 262144                  // 64^3
#define KBINS 20
#define NEDGE 21
#define THREADS 256
#define NBLOCKS 2048                 // 8 blocks/CU -> 32 waves/CU (best TLP, R7)
#define CPB 11                       // chunks (1024 elems) per block; zero tail
#define CPC 256                      // chunks per channel
#define HSTRIDE 23                   // 22 slots + pad; gcd(23,32)=1
#define ROWSET (64 * HSTRIDE)

// Lean hybrid: a-operand -> 1 ds_atomic/pair (DS pipe, half of R7's load);
// b-operand -> R5-validated byte-thermometer CDF in 3x64-bit VGPRs (VALU pipe,
// ~15 inst/elem, no flush: <=44 counts fits a biased byte). R7's proven
// memset+global-atomic+tiny-final structure (R12 showed slot-finals cost +22us).
__global__ void __launch_bounds__(THREADS)
binloss_main(const float* __restrict__ inp, const float* __restrict__ tar,
             const float* __restrict__ br, int* __restrict__ g_hist,
             float* __restrict__ partials)
{
    __shared__ int          rows[ROWSET];        // 5888 B: a-side per-lane rows
    __shared__ unsigned int brow[THREADS][7];    // 7168 B: b-side byte dumps
    __shared__ int          aq[4][KBINS],  bq[4][NEDGE];
    __shared__ int          aq0[4][KBINS], bq0[4][NEDGE];   // boundary seg0
    __shared__ float        wsum[4];

    const int tid = threadIdx.x, lane = tid & 63;
    for (int i = tid; i < ROWSET; i += THREADS) rows[i] = 0;

    const float e0     = br[0];
    const float eK     = br[2 * KBINS - 1];
    const float inv_w  = (float)KBINS / (eK - e0);
    const float shift1 = 1.0f - e0 * inv_w;      // +1 folded: (int) trunc == floor
    const float tmax   = 21.5f;
    __syncthreads();

    const int fc  = blockIdx.x * CPB;
    const int ch0 = fc >> 8;
    const int rem = fc & (CPC - 1);
    const int n1  = (rem + CPB > CPC) ? (CPC - rem) : CPB;  // chunks in ch0

    const float4* pa = (const float4*)inp + (size_t)fc * 256 + tid;
    const float4* pb = (const float4*)tar + (size_t)fc * 256 + tid;

    int* rw = &rows[lane * HSTRIDE];

    const unsigned long long ONES  = 0x0101010101010101ull;
    const unsigned long long BIASC = 0x8080808080808080ull;
    unsigned long long H0 = BIASC, H1 = BIASC, H2 = BIASC;  // byte j: #(sb<=j)
    float s_lin = 0.f, s_quad = 0.f;

    for (int k = 0; k < CPB; ++k) {
        if (k == n1) {                 // block-uniform channel boundary (87 blocks)
            __syncthreads();           // all a-atomics for seg0 done
            brow[tid][0] = (unsigned int)H0; brow[tid][1] = (unsigned int)(H0 >> 32);
            brow[tid][2] = (unsigned int)H1; brow[tid][3] = (unsigned int)(H1 >> 32);
            brow[tid][4] = (unsigned int)H2; brow[tid][5] = (unsigned int)(H2 >> 32);
            H0 = BIASC; H1 = BIASC; H2 = BIASC;
            __syncthreads();
            if (tid < 80) {            // fold seg0 a-rows
                const int j = tid % KBINS, qr = tid / KBINS;
                int s = 0;
#pragma unroll
                for (int rr = qr * 16; rr < qr * 16 + 16; ++rr)
                    s += rows[rr * HSTRIDE + 1 + j];
                aq0[qr][j] = s;
            } else if (tid < 164) {    // fold seg0 b-bytes (4 qr x 21 edges)
                const int idx = tid - 80, qr = idx / NEDGE, j = idx % NEDGE;
                const int dw = j >> 2, sh = 8 * (j & 3);
                int s = 0;
                for (int r = qr * 64; r < qr * 64 + 64; ++r)
                    s += (int)((brow[r][dw] >> sh) & 0xFFu);
                bq0[qr][j] = s;
            }
            __syncthreads();
            for (int i = tid; i < ROWSET; i += THREADS) rows[i] = 0;
            __syncthreads();
        }
        float4 a = pa[k * 256];
        float4 b = pb[k * 256];
#pragma unroll
        for (int q = 0; q < 4; ++q) {
            float av = (&a.x)[q], bv = (&b.x)[q];
            float d = fabsf(av - bv);
            s_lin += fmaxf(d, 1.0f);             // -1 hoisted out
            float m = fminf(d, 1.0f);
            s_quad  = __builtin_fmaf(m, m, s_quad);
            // a: med3 bin -> DS atomic (slots 0,21 trash)
            int sa = (int)__builtin_amdgcn_fmed3f(__builtin_fmaf(av, inv_w, shift1), 0.0f, tmax);
            atomicAdd(&rw[sa], 1);
            // b: byte thermometer, +1 to every byte j >= sb (validated in R5)
            int sb = (int)__builtin_amdgcn_fmed3f(__builtin_fmaf(bv, inv_w, shift1), 0.0f, tmax);
            unsigned long long P = ONES << ((8 * sb) & 63);
            bool l8 = sb < 8, l16 = sb < 16;
            H0 += l8 ? P : 0ull;
            H1 += l8 ? ONES : (l16 ? P : 0ull);
            H2 += l16 ? ONES : P;
        }
    }

    // SmoothL1 wave(64) reduce
    float sl1 = (s_lin - (float)(CPB * 4)) + 0.5f * s_quad;
#pragma unroll
    for (int off = 32; off > 0; off >>= 1) sl1 += __shfl_down(sl1, off, 64);
    if (lane == 0) wsum[tid >> 6] = sl1;

    // dump last-segment thermometer
    brow[tid][0] = (unsigned int)H0; brow[tid][1] = (unsigned int)(H0 >> 32);
    brow[tid][2] = (unsigned int)H1; brow[tid][3] = (unsigned int)(H1 >> 32);
    brow[tid][4] = (unsigned int)H2; brow[tid][5] = (unsigned int)(H2 >> 32);
    __syncthreads();                 // covers rows atomics, brow, wsum

    if (tid == 0)
        partials[blockIdx.x] = wsum[0] + wsum[1] + wsum[2] + wsum[3];

    if (tid < 80) {                  // fold last-seg a-rows
        const int j = tid % KBINS, qr = tid / KBINS;
        int s = 0;
#pragma unroll
        for (int rr = qr * 16; rr < qr * 16 + 16; ++rr)
            s += rows[rr * HSTRIDE + 1 + j];
        aq[qr][j] = s;
    } else if (tid < 164) {          // fold last-seg b-bytes
        const int idx = tid - 80, qr = idx / NEDGE, j = idx % NEDGE;
        const int dw = j >> 2, sh = 8 * (j & 3);
        int s = 0;
        for (int r = qr * 64; r < qr * 64 + 64; ++r)
            s += (int)((brow[r][dw] >> sh) & 0xFFu);
        bq[qr][j] = s;
    }
    __syncthreads();

    // combine: hist = a_count - (B[j+1]-B[j]); bias cancels in the difference
    const int ch_last = (n1 < CPB) ? ch0 + 1 : ch0;
    if (tid < KBINS) {
        const int j = tid;
        int a4  = aq[0][j] + aq[1][j] + aq[2][j] + aq[3][j];
        int blo = bq[0][j] + bq[1][j] + bq[2][j] + bq[3][j];
        int bhi = bq[0][j + 1] + bq[1][j + 1] + bq[2][j + 1] + bq[3][j + 1];
        int v = a4 - (bhi - blo);
        if (v) atomicAdd(&g_hist[ch_last * KBINS + j], v);
    } else if (tid >= 64 && tid < 64 + KBINS && n1 < CPB) {
        const int j = tid - 64;
        int a4  = aq0[0][j] + aq0[1][j] + aq0[2][j] + aq0[3][j];
        int blo = bq0[0][j] + bq0[1][j] + bq0[2][j] + bq0[3][j];
        int bhi = bq0[0][j + 1] + bq0[1][j + 1] + bq0[2][j + 1] + bq0[3][j + 1];
        int v = a4 - (bhi - blo);
        if (v) atomicAdd(&g_hist[ch0 * KBINS + j], v);
    }
}

__global__ void __launch_bounds__(256)
binloss_final(const int* __restrict__ g_hist, const float* __restrict__ partials,
              float* __restrict__ out)
{
    __shared__ double r1[256];
    __shared__ double r2[256];
    const int tid = threadIdx.x;
    double s1 = 0.0, s2 = 0.0;
    for (int i = tid; i < NBLOCKS; i += 256) s1 += (double)partials[i];
    for (int i = tid; i < BC * KBINS; i += 256) s2 += fabs((double)g_hist[i]);
    r1[tid] = s1; r2[tid] = s2;
    __syncthreads();
    for (int off = 128; off > 0; off >>= 1) {
        if (tid < off) { r1[tid] += r1[tid + off]; r2[tid] += r2[tid + off]; }
        __syncthreads();
    }
    if (tid == 0) {
        const double ntot  = (double)BC * (double)NVOX;
        double loss1 = r1[0] / ntot;
        double loss2 = r2[0] / ((double)NVOX * (double)(BC * KBINS));
        out[0] = (float)(0.5 * loss1 + 0.5 * loss2);
    }
}

extern "C" void kernel_launch(void* const* d_in, const int* in_sizes, int n_in,
                              void* d_out, int out_size, void* d_ws, size_t ws_size,
                              hipStream_t stream) {
    const float* inp = (const float*)d_in[0];
    const float* tar = (const float*)d_in[1];
    const float* br  = (const float*)d_in[2];

    int*   g_hist   = (int*)d_ws;
    float* partials = (float*)((char*)d_ws + BC * KBINS * sizeof(int));

    // histogram accumulated with atomics -> zero every call (cheap, R12 lesson)
    hipMemsetAsync(d_ws, 0, BC * KBINS * sizeof(int), stream);

    binloss_main<<<NBLOCKS, THREADS, 0, stream>>>(inp, tar, br, g_hist, partials);
    binloss_final<<<1, 256, 0, stream>>>(g_hist, partials, (float*)d_out);
}